// Round 13
// baseline (165.673 us; speedup 1.0000x reference)
//
#include <hip/hip_runtime.h>

// GIN: 2x GINConv(eps=0), N=50000, E=800000, d=128. bf16 + MFMA.
// R13: R8 conv (best: 132.8us) + per-node edge lists SORTED BY SRC.
// Rationale: R7-R12 all show FETCH=76MB @ ~2.2TB/s regardless of structure
// -> gather is L3 random-service bound on L2 misses. src-ascending scans put
// all ~1500 concurrent node-scans in approximate lock-step through src space
// -> instantaneous working set ~few MB -> fits per-XCD L2 -> fewer misses.
// LPT (R12, -30us regression) reverted.
// ws: [ xb | zb | wt | gcnt | ebuf | sbuf | noff ]

#define NN 50000
#define NE 800000
#define FD 128
#define BNODES 64
#define NB 782           // ceil(NN/64); bucket 781 has 16 nodes
#define BCAP 1536        // max edges/bucket: mean 1024, sigma 32 -> +16 sigma
#define EPW 4096
#define NWG_BIN 196      // ceil(NE/EPW)

typedef unsigned short u16;
typedef unsigned int u32;
typedef __attribute__((ext_vector_type(8))) short bf16x8;
typedef __attribute__((ext_vector_type(4))) float f32x4;

static __device__ __forceinline__ float b2f(u16 u) {
    return __uint_as_float(((u32)u) << 16);
}
static __device__ __forceinline__ u16 f2b(float f) {
    u32 x = __float_as_uint(f);
    u32 r = x + 0x7FFFu + ((x >> 16) & 1u);   // RNE
    return (u16)(r >> 16);
}

// unpack-accumulate a uint4 (8 bf16) into acc0/acc1 via exact float-bit tricks
#define ACCUM(v) do { \
    acc0.x += __uint_as_float((v).x << 16); \
    acc0.y += __uint_as_float((v).x & 0xFFFF0000u); \
    acc0.z += __uint_as_float((v).y << 16); \
    acc0.w += __uint_as_float((v).y & 0xFFFF0000u); \
    acc1.x += __uint_as_float((v).z << 16); \
    acc1.y += __uint_as_float((v).z & 0xFFFF0000u); \
    acc1.z += __uint_as_float((v).w << 16); \
    acc1.w += __uint_as_float((v).w & 0xFFFF0000u); } while (0)

// ---------------- converts ----------------

__global__ __launch_bounds__(256) void convert_x_kernel(
    const float* __restrict__ x, u16* __restrict__ xb)
{
    int gid = blockIdx.x * 256 + threadIdx.x;
    size_t base = (size_t)gid * 8;
    float4 a = *reinterpret_cast<const float4*>(x + base);
    float4 b = *reinterpret_cast<const float4*>(x + base + 4);
    u32 w0 = (u32)f2b(a.x) | ((u32)f2b(a.y) << 16);
    u32 w1 = (u32)f2b(a.z) | ((u32)f2b(a.w) << 16);
    u32 w2 = (u32)f2b(b.x) | ((u32)f2b(b.y) << 16);
    u32 w3 = (u32)f2b(b.z) | ((u32)f2b(b.w) << 16);
    uint4 o = {w0, w1, w2, w3};
    *reinterpret_cast<uint4*>(xb + base) = o;
}

// W [128][128] fp32 row-major -> WT[n][k] = W[k][n] bf16; block 4 zeroes gcnt
__global__ __launch_bounds__(256) void convert_w_kernel(
    const float* __restrict__ w0, const float* __restrict__ w1,
    const float* __restrict__ w2, const float* __restrict__ w3,
    u16* __restrict__ wt, int* __restrict__ gcnt)
{
    int b = blockIdx.x;
    if (b == 4) {
        if (threadIdx.x < NB) {
            for (int i = threadIdx.x; i < NB; i += 256) gcnt[i] = 0;
        }
        return;
    }
    const float* W = (b == 0) ? w0 : (b == 1) ? w1 : (b == 2) ? w2 : w3;
    u16* out = wt + (size_t)b * FD * FD;
    for (int idx = threadIdx.x; idx < FD * FD; idx += 256) {
        int n = idx >> 7, k = idx & 127;
        out[idx] = f2b(W[k * FD + n]);
    }
}

// ---------------- bucket binning (64-node buckets) ----------------

__global__ __launch_bounds__(256) void bin_kernel(
    const int* __restrict__ ei, u32* __restrict__ ebuf, int* __restrict__ gcnt)
{
    __shared__ int cnt[1024];
    __shared__ int lofs[1024];
    __shared__ int cur[1024];
    __shared__ int gb[1024];
    __shared__ int csum[16];
    __shared__ int cofs[16];
    __shared__ u32 vals[EPW];
    __shared__ u16 bkt[EPW];

    const int tid = threadIdx.x, lane = tid & 63, wv = tid >> 6;
    const int e0 = blockIdx.x * EPW;
    const int nE = min(EPW, NE - e0);
    const int* dstp = ei + NE;

    for (int i = tid; i < 1024; i += 256) { cnt[i] = 0; cur[i] = 0; }
    __syncthreads();

    for (int k = 0; k < EPW / 256; ++k) {
        int e = e0 + k * 256 + tid;
        if (e < NE) atomicAdd(&cnt[(u32)dstp[e] >> 6], 1);
    }
    __syncthreads();

    // exclusive scan over 1024 slots (16 chunks of 64)
    for (int cc = 0; cc < 4; ++cc) {
        int c = wv + cc * 4;
        int i = c * 64 + lane;
        int v = cnt[i];
        int sc = v;
#pragma unroll
        for (int s = 1; s < 64; s <<= 1) {
            int t = __shfl_up(sc, s);
            if (lane >= s) sc += t;
        }
        lofs[i] = sc - v;
        if (lane == 63) csum[c] = sc;
    }
    __syncthreads();
    if (wv == 0) {
        int s = (lane < 16) ? csum[lane] : 0;
        int sc = s;
#pragma unroll
        for (int st = 1; st < 16; st <<= 1) {
            int u = __shfl_up(sc, st);
            if (lane >= st) sc += u;
        }
        if (lane < 16) cofs[lane] = sc - s;
    }
    __syncthreads();
    for (int cc = 0; cc < 4; ++cc) {
        int c = wv + cc * 4;
        lofs[c * 64 + lane] += cofs[c];
    }
    __syncthreads();

    // place (bucket-grouped in LDS)
    for (int k = 0; k < EPW / 256; ++k) {
        int e = e0 + k * 256 + tid;
        if (e < NE) {
            int s = ei[e];
            u32 d = (u32)dstp[e];
            int b = d >> 6;
            int p = lofs[b] + atomicAdd(&cur[b], 1);
            vals[p] = (u32)s | ((d & 63u) << 16);
            bkt[p] = (u16)b;
        }
    }
    __syncthreads();

    // claim global chunks
    for (int b = tid; b < NB; b += 256) {
        int c = cur[b];
        gb[b] = c ? atomicAdd(&gcnt[b], c) : 0;
    }
    __syncthreads();

    // flush bucket-grouped -> contiguous runs
    for (int idx = tid; idx < nE; idx += 256) {
        int b = bkt[idx];
        ebuf[(size_t)b * BCAP + gb[b] + (idx - lofs[b])] = vals[idx];
    }
}

// ---------------- one-time counting sort per bucket + per-node src-sort ----

__global__ __launch_bounds__(256) void sort_kernel(
    const u32* __restrict__ ebuf, const int* __restrict__ gcnt,
    u16* __restrict__ sbuf, int* __restrict__ noff)
{
    __shared__ u32 stage[BCAP];    // 6 KB
    __shared__ u16 sorted[BCAP];   // 3 KB
    __shared__ int cnt64[64];
    __shared__ int off64[65];
    __shared__ int cur64[64];

    const int tid = threadIdx.x, lane = tid & 63, wv = tid >> 6;
    const int b = blockIdx.x;
    const int cnt = gcnt[b];
    const u32* eb = ebuf + (size_t)b * BCAP;

    if (tid < 64) cnt64[tid] = 0;
    __syncthreads();

    for (int e = tid; e < cnt; e += 256) {
        u32 v = eb[e];
        stage[e] = v;
        atomicAdd(&cnt64[v >> 16], 1);
    }
    __syncthreads();

    if (wv == 0) {
        int v = cnt64[lane];
        int sc = v;
#pragma unroll
        for (int s = 1; s < 64; s <<= 1) {
            int t = __shfl_up(sc, s);
            if (lane >= s) sc += t;
        }
        off64[lane + 1] = sc;
        cur64[lane] = sc - v;
        if (lane == 0) off64[0] = 0;
    }
    __syncthreads();

    for (int e = tid; e < cnt; e += 256) {
        u32 v = stage[e];
        int pos = atomicAdd(&cur64[v >> 16], 1);
        sorted[pos] = (u16)(v & 0xFFFFu);   // src < 50000 fits u16
    }
    __syncthreads();

    // per-node src-ascending insertion sort (lane n owns node n's run).
    // Purpose: all concurrent node-scans sweep src-space in lock-step ->
    // instantaneous working set fits per-XCD L2 -> fewer L3-serviced misses.
    if (tid < 64) {
        const int beg = off64[tid], end = off64[tid + 1];
        for (int i = beg + 1; i < end; ++i) {
            u16 key = sorted[i];
            int j = i - 1;
            while (j >= beg && sorted[j] > key) { sorted[j + 1] = sorted[j]; --j; }
            sorted[j + 1] = key;
        }
    }
    __syncthreads();

    if (tid < 65) noff[b * 65 + tid] = off64[tid];
    u32* sb = (u32*)(sbuf + (size_t)b * BCAP);
    const u32* so = (const u32*)sorted;
    for (int i = tid; i * 2 < cnt; i += 256) sb[i] = so[i];
}

// ---------------- fused conv (R8 structure, src-sorted edge lists) --------
// Block = bucket = M-tile (64 nodes). 8 waves. Gather: 16-lane group per node
// (4 nodes/wave, 2 q-iters), dwordx4 row reads, 4-deep register batches,
// float-bit unpack. GEMM: 8 waves as 2Mx4N; weights from global (L2-resident).
// k-map phi(g,i)=8g+i both operands; D: col=lane&15, row=(lane>>4)*4+reg.

template <bool F32OUT>
__global__ __launch_bounds__(512, 6) void conv_kernel(
    const u16* __restrict__ h, const u16* __restrict__ sbuf,
    const int* __restrict__ noff,
    const u16* __restrict__ WTa, const float* __restrict__ biasa,
    const u16* __restrict__ WTb, const float* __restrict__ biasb,
    void* __restrict__ outv)
{
    __shared__ u16 a_lds[64][136];   // 17.4 KB
    __shared__ u16 t_lds[64][136];   // 17.4 KB
    __shared__ u16 sorted[BCAP];     // 3 KB
    __shared__ int off[65];

    const int tid = threadIdx.x;
    const int lane = tid & 63;
    const int wv = tid >> 6;         // 0..7
    const int b = blockIdx.x;
    const int node0 = b * BNODES;
    const int nNodes = min(BNODES, NN - node0);
    const int g = lane >> 4;         // group 0..3
    const int l16 = lane & 15;

    // ---- phase 1: load sorted edge list + offsets ----
    if (tid < 65) off[tid] = noff[b * 65 + tid];
    __syncthreads();
    const int cnt = off[64];
    {
        const u32* sb = (const u32*)(sbuf + (size_t)b * BCAP);
        u32* so = (u32*)sorted;
        for (int i = tid; i * 2 < cnt; i += 512) so[i] = sb[i];
    }
    __syncthreads();

    // ---- phase 2: gather into a_lds (group g handles node q*4+g) ----
    const u16* hcol = h + l16 * 8;   // this lane's 8-feature slice

    for (int q = wv; q < 16; q += 8) {
        const int n = q * 4 + g;
        float4 acc0 = {0.f, 0.f, 0.f, 0.f};
        float4 acc1 = {0.f, 0.f, 0.f, 0.f};
        if (n < nNodes) {
            uint4 v = *reinterpret_cast<const uint4*>(hcol + (size_t)(node0 + n) * FD);
            ACCUM(v);   // self term
            const int end = off[n + 1];
            const int endm1 = end - 1;
            for (int e = off[n]; e < end; e += 4) {
                const int m = end - e;
                uint4 vv[4];
#pragma unroll
                for (int k = 0; k < 4; ++k) {
                    int ee = e + k; if (ee > endm1) ee = endm1;  // dup tail: L1-hit
                    vv[k] = *reinterpret_cast<const uint4*>(
                        hcol + (size_t)sorted[ee] * FD);
                }
                ACCUM(vv[0]);
                if (m > 1) ACCUM(vv[1]);
                if (m > 2) ACCUM(vv[2]);
                if (m > 3) ACCUM(vv[3]);
            }
        }
        uint4 o;
        o.x = (u32)f2b(acc0.x) | ((u32)f2b(acc0.y) << 16);
        o.y = (u32)f2b(acc0.z) | ((u32)f2b(acc0.w) << 16);
        o.z = (u32)f2b(acc1.x) | ((u32)f2b(acc1.y) << 16);
        o.w = (u32)f2b(acc1.z) | ((u32)f2b(acc1.w) << 16);
        *reinterpret_cast<uint4*>(&a_lds[n][l16 * 8]) = o;   // zeros for pad rows
    }
    __syncthreads();

    const int mbase = (wv >> 2) * 32;   // 0 or 32
    const int nbase = (wv & 3) * 32;    // 0,32,64,96

    // ---- phase 3: t = relu(a @ Wa + ba) ----
    f32x4 acc[2][2];
#pragma unroll
    for (int m = 0; m < 2; ++m)
#pragma unroll
        for (int nf = 0; nf < 2; ++nf) acc[m][nf] = (f32x4){0.f, 0.f, 0.f, 0.f};

#pragma unroll
    for (int k0 = 0; k0 < 4; ++k0) {
        const int kk = k0 * 32 + g * 8;
        bf16x8 a0 = *reinterpret_cast<const bf16x8*>(&a_lds[mbase + l16][kk]);
        bf16x8 a1 = *reinterpret_cast<const bf16x8*>(&a_lds[mbase + 16 + l16][kk]);
#pragma unroll
        for (int nf = 0; nf < 2; ++nf) {
            bf16x8 bb = *reinterpret_cast<const bf16x8*>(
                WTa + (size_t)(nbase + nf * 16 + l16) * FD + kk);
            acc[0][nf] = __builtin_amdgcn_mfma_f32_16x16x32_bf16(a0, bb, acc[0][nf], 0, 0, 0);
            acc[1][nf] = __builtin_amdgcn_mfma_f32_16x16x32_bf16(a1, bb, acc[1][nf], 0, 0, 0);
        }
    }

#pragma unroll
    for (int m = 0; m < 2; ++m) {
#pragma unroll
        for (int nf = 0; nf < 2; ++nf) {
            int col = nbase + nf * 16 + l16;
            float bc = biasa[col];
#pragma unroll
            for (int r = 0; r < 4; ++r) {
                int row = mbase + 16 * m + g * 4 + r;
                t_lds[row][col] = f2b(fmaxf(acc[m][nf][r] + bc, 0.f));
            }
        }
    }
    __syncthreads();

    // ---- phase 4: out = relu(t @ Wb + bb) ----
    f32x4 acc2[2][2];
#pragma unroll
    for (int m = 0; m < 2; ++m)
#pragma unroll
        for (int nf = 0; nf < 2; ++nf) acc2[m][nf] = (f32x4){0.f, 0.f, 0.f, 0.f};

#pragma unroll
    for (int k0 = 0; k0 < 4; ++k0) {
        const int kk = k0 * 32 + g * 8;
        bf16x8 a0 = *reinterpret_cast<const bf16x8*>(&t_lds[mbase + l16][kk]);
        bf16x8 a1 = *reinterpret_cast<const bf16x8*>(&t_lds[mbase + 16 + l16][kk]);
#pragma unroll
        for (int nf = 0; nf < 2; ++nf) {
            bf16x8 bb = *reinterpret_cast<const bf16x8*>(
                WTb + (size_t)(nbase + nf * 16 + l16) * FD + kk);
            acc2[0][nf] = __builtin_amdgcn_mfma_f32_16x16x32_bf16(a0, bb, acc2[0][nf], 0, 0, 0);
            acc2[1][nf] = __builtin_amdgcn_mfma_f32_16x16x32_bf16(a1, bb, acc2[1][nf], 0, 0, 0);
        }
    }

    if (F32OUT) {
        // f32 frag stores are already full-line (16 consecutive f32 = 64B)
#pragma unroll
        for (int m = 0; m < 2; ++m) {
#pragma unroll
            for (int nf = 0; nf < 2; ++nf) {
                int col = nbase + nf * 16 + l16;
                float bc = biasb[col];
#pragma unroll
                for (int r = 0; r < 4; ++r) {
                    int row = node0 + mbase + 16 * m + g * 4 + r;
                    if (row < NN) {
                        float v = fmaxf(acc2[m][nf][r] + bc, 0.f);
                        reinterpret_cast<float*>(outv)[(size_t)row * FD + col] = v;
                    }
                }
            }
        }
    } else {
        // stage bf16 result in t_lds (free after phase 4 reads), then
        // coalesced 16B/lane copy-out — avoids 2x partial-line writebacks.
        __syncthreads();
#pragma unroll
        for (int m = 0; m < 2; ++m) {
#pragma unroll
            for (int nf = 0; nf < 2; ++nf) {
                int col = nbase + nf * 16 + l16;
                float bc = biasb[col];
#pragma unroll
                for (int r = 0; r < 4; ++r) {
                    int row = mbase + 16 * m + g * 4 + r;
                    t_lds[row][col] = f2b(fmaxf(acc2[m][nf][r] + bc, 0.f));
                }
            }
        }
        __syncthreads();
        u16* outp = reinterpret_cast<u16*>(outv);
#pragma unroll
        for (int it = 0; it < 2; ++it) {
            int idx = tid + it * 512;
            int r = idx >> 4, c = (idx & 15) * 8;
            if (node0 + r < NN)
                *reinterpret_cast<uint4*>(outp + (size_t)(node0 + r) * FD + c) =
                    *reinterpret_cast<const uint4*>(&t_lds[r][c]);
        }
    }
}

extern "C" void kernel_launch(void* const* d_in, const int* in_sizes, int n_in,
                              void* d_out, int out_size, void* d_ws, size_t ws_size,
                              hipStream_t stream) {
    const float* x   = (const float*)d_in[0];
    const int*   ei  = (const int*)d_in[1];
    const float* W1a = (const float*)d_in[2];
    const float* b1a = (const float*)d_in[3];
    const float* W1b = (const float*)d_in[4];
    const float* b1b = (const float*)d_in[5];
    const float* W2a = (const float*)d_in[6];
    const float* b2a = (const float*)d_in[7];
    const float* W2b = (const float*)d_in[8];
    const float* b2b = (const float*)d_in[9];

    const size_t feat = (size_t)NN * FD;
    u16* xb = (u16*)d_ws;             // 12.8 MB (x bf16)
    u16* zb = xb + feat;              // 12.8 MB (h1 bf16)
    u16* wt = zb + feat;              // 128 KB
    int* gcnt = (int*)(wt + 4 * FD * FD);         // 1024 ints
    u32* ebuf = (u32*)(gcnt + 1024);              // NB*BCAP*4 = 4.80 MB
    u16* sbuf = (u16*)(ebuf + (size_t)NB * BCAP); // NB*BCAP*2 = 2.40 MB
    int* noff = (int*)(sbuf + (size_t)NB * BCAP); // NB*65*4 = 204 KB

    const int cBlocks = (int)(feat / (256 * 8));  // 3125

    convert_x_kernel<<<cBlocks, 256, 0, stream>>>(x, xb);
    convert_w_kernel<<<5, 256, 0, stream>>>(W1a, W1b, W2a, W2b, wt, gcnt);

    bin_kernel<<<NWG_BIN, 256, 0, stream>>>(ei, ebuf, gcnt);
    sort_kernel<<<NB, 256, 0, stream>>>(ebuf, gcnt, sbuf, noff);

    // conv1: xb -> zb (bf16)
    conv_kernel<false><<<NB, 512, 0, stream>>>(
        xb, sbuf, noff, wt, b1a, wt + 1 * FD * FD, b1b, zb);
    // conv2: zb -> d_out (fp32)
    conv_kernel<true><<<NB, 512, 0, stream>>>(
        zb, sbuf, noff, wt + 2 * FD * FD, b2a, wt + 3 * FD * FD, b2b, (float*)d_out);
}

// Round 14
// 158.620 us; speedup vs baseline: 1.0445x; 1.0445x over previous
//
#include <hip/hip_runtime.h>

// GIN: 2x GINConv(eps=0), N=50000, E=800000, d=128. bf16 + MFMA.
// R14: R13 minus the 48us insertion sort. Ascending sort of packed
// (dst_local<<16)|src u32s == dst-major + src-ascending-per-node, done as one
// LDS bitonic over 2048 padded entries (~2us/block, all blocks co-resident).
// R13 proved src-sorted lists cut conv ~5us each (L2 lock-step locality);
// this keeps the benefit and removes the cost.
// ws: [ xb | zb | wt | gcnt | ebuf | sbuf | noff ]

#define NN 50000
#define NE 800000
#define FD 128
#define BNODES 64
#define NB 782           // ceil(NN/64); bucket 781 has 16 nodes
#define BCAP 1536        // max edges/bucket: mean 1024, sigma 32 -> +16 sigma
#define EPW 4096
#define NWG_BIN 196      // ceil(NE/EPW)

typedef unsigned short u16;
typedef unsigned int u32;
typedef __attribute__((ext_vector_type(8))) short bf16x8;
typedef __attribute__((ext_vector_type(4))) float f32x4;

static __device__ __forceinline__ float b2f(u16 u) {
    return __uint_as_float(((u32)u) << 16);
}
static __device__ __forceinline__ u16 f2b(float f) {
    u32 x = __float_as_uint(f);
    u32 r = x + 0x7FFFu + ((x >> 16) & 1u);   // RNE
    return (u16)(r >> 16);
}

// unpack-accumulate a uint4 (8 bf16) into acc0/acc1 via exact float-bit tricks
#define ACCUM(v) do { \
    acc0.x += __uint_as_float((v).x << 16); \
    acc0.y += __uint_as_float((v).x & 0xFFFF0000u); \
    acc0.z += __uint_as_float((v).y << 16); \
    acc0.w += __uint_as_float((v).y & 0xFFFF0000u); \
    acc1.x += __uint_as_float((v).z << 16); \
    acc1.y += __uint_as_float((v).z & 0xFFFF0000u); \
    acc1.z += __uint_as_float((v).w << 16); \
    acc1.w += __uint_as_float((v).w & 0xFFFF0000u); } while (0)

// ---------------- converts ----------------

__global__ __launch_bounds__(256) void convert_x_kernel(
    const float* __restrict__ x, u16* __restrict__ xb)
{
    int gid = blockIdx.x * 256 + threadIdx.x;
    size_t base = (size_t)gid * 8;
    float4 a = *reinterpret_cast<const float4*>(x + base);
    float4 b = *reinterpret_cast<const float4*>(x + base + 4);
    u32 w0 = (u32)f2b(a.x) | ((u32)f2b(a.y) << 16);
    u32 w1 = (u32)f2b(a.z) | ((u32)f2b(a.w) << 16);
    u32 w2 = (u32)f2b(b.x) | ((u32)f2b(b.y) << 16);
    u32 w3 = (u32)f2b(b.z) | ((u32)f2b(b.w) << 16);
    uint4 o = {w0, w1, w2, w3};
    *reinterpret_cast<uint4*>(xb + base) = o;
}

// W [128][128] fp32 row-major -> WT[n][k] = W[k][n] bf16; block 4 zeroes gcnt
__global__ __launch_bounds__(256) void convert_w_kernel(
    const float* __restrict__ w0, const float* __restrict__ w1,
    const float* __restrict__ w2, const float* __restrict__ w3,
    u16* __restrict__ wt, int* __restrict__ gcnt)
{
    int b = blockIdx.x;
    if (b == 4) {
        for (int i = threadIdx.x; i < NB; i += 256) gcnt[i] = 0;
        return;
    }
    const float* W = (b == 0) ? w0 : (b == 1) ? w1 : (b == 2) ? w2 : w3;
    u16* out = wt + (size_t)b * FD * FD;
    for (int idx = threadIdx.x; idx < FD * FD; idx += 256) {
        int n = idx >> 7, k = idx & 127;
        out[idx] = f2b(W[k * FD + n]);
    }
}

// ---------------- bucket binning (64-node buckets) ----------------

__global__ __launch_bounds__(256) void bin_kernel(
    const int* __restrict__ ei, u32* __restrict__ ebuf, int* __restrict__ gcnt)
{
    __shared__ int cnt[1024];
    __shared__ int lofs[1024];
    __shared__ int cur[1024];
    __shared__ int gb[1024];
    __shared__ int csum[16];
    __shared__ int cofs[16];
    __shared__ u32 vals[EPW];
    __shared__ u16 bkt[EPW];

    const int tid = threadIdx.x, lane = tid & 63, wv = tid >> 6;
    const int e0 = blockIdx.x * EPW;
    const int nE = min(EPW, NE - e0);
    const int* dstp = ei + NE;

    for (int i = tid; i < 1024; i += 256) { cnt[i] = 0; cur[i] = 0; }
    __syncthreads();

    for (int k = 0; k < EPW / 256; ++k) {
        int e = e0 + k * 256 + tid;
        if (e < NE) atomicAdd(&cnt[(u32)dstp[e] >> 6], 1);
    }
    __syncthreads();

    // exclusive scan over 1024 slots (16 chunks of 64)
    for (int cc = 0; cc < 4; ++cc) {
        int c = wv + cc * 4;
        int i = c * 64 + lane;
        int v = cnt[i];
        int sc = v;
#pragma unroll
        for (int s = 1; s < 64; s <<= 1) {
            int t = __shfl_up(sc, s);
            if (lane >= s) sc += t;
        }
        lofs[i] = sc - v;
        if (lane == 63) csum[c] = sc;
    }
    __syncthreads();
    if (wv == 0) {
        int s = (lane < 16) ? csum[lane] : 0;
        int sc = s;
#pragma unroll
        for (int st = 1; st < 16; st <<= 1) {
            int u = __shfl_up(sc, st);
            if (lane >= st) sc += u;
        }
        if (lane < 16) cofs[lane] = sc - s;
    }
    __syncthreads();
    for (int cc = 0; cc < 4; ++cc) {
        int c = wv + cc * 4;
        lofs[c * 64 + lane] += cofs[c];
    }
    __syncthreads();

    // place (bucket-grouped in LDS)
    for (int k = 0; k < EPW / 256; ++k) {
        int e = e0 + k * 256 + tid;
        if (e < NE) {
            int s = ei[e];
            u32 d = (u32)dstp[e];
            int b = d >> 6;
            int p = lofs[b] + atomicAdd(&cur[b], 1);
            vals[p] = (u32)s | ((d & 63u) << 16);
            bkt[p] = (u16)b;
        }
    }
    __syncthreads();

    // claim global chunks
    for (int b = tid; b < NB; b += 256) {
        int c = cur[b];
        gb[b] = c ? atomicAdd(&gcnt[b], c) : 0;
    }
    __syncthreads();

    // flush bucket-grouped -> contiguous runs
    for (int idx = tid; idx < nE; idx += 256) {
        int b = bkt[idx];
        ebuf[(size_t)b * BCAP + gb[b] + (idx - lofs[b])] = vals[idx];
    }
}

// ---------------- one-time per-bucket sort: bitonic over packed u32 --------
// Ascending sort of (dst_local<<16)|src == dst-major, src-ascending per node.

__global__ __launch_bounds__(256) void sort_kernel(
    const u32* __restrict__ ebuf, const int* __restrict__ gcnt,
    u16* __restrict__ sbuf, int* __restrict__ noff)
{
    __shared__ u32 stage[2048];    // 8 KB (padded to pow2 with 0xFFFFFFFF)
    __shared__ int cnt64[64];
    __shared__ int off64[65];

    const int tid = threadIdx.x, lane = tid & 63, wv = tid >> 6;
    const int b = blockIdx.x;
    const int cnt = gcnt[b];
    const u32* eb = ebuf + (size_t)b * BCAP;

    if (tid < 64) cnt64[tid] = 0;
    __syncthreads();

    for (int i = tid; i < 2048; i += 256) {
        u32 v = 0xFFFFFFFFu;
        if (i < cnt) {
            v = eb[i];
            atomicAdd(&cnt64[v >> 16], 1);
        }
        stage[i] = v;
    }
    __syncthreads();

    // bitonic ascending sort of 2048 entries; 256 threads x 4 pairs/step
    for (int k = 2; k <= 2048; k <<= 1) {
        for (int j = k >> 1; j > 0; j >>= 1) {
#pragma unroll
            for (int t4 = 0; t4 < 4; ++t4) {
                int t = tid + t4 * 256;
                int i = ((t & ~(j - 1)) << 1) | (t & (j - 1));
                int ixj = i | j;
                u32 a = stage[i], c = stage[ixj];
                bool up = ((i & k) == 0);
                if ((a > c) == up) { stage[i] = c; stage[ixj] = a; }
            }
            __syncthreads();
        }
    }

    if (wv == 0) {
        int v = cnt64[lane];
        int sc = v;
#pragma unroll
        for (int s = 1; s < 64; s <<= 1) {
            int t = __shfl_up(sc, s);
            if (lane >= s) sc += t;
        }
        off64[lane + 1] = sc;
        if (lane == 0) off64[0] = 0;
    }
    __syncthreads();

    if (tid < 65) noff[b * 65 + tid] = off64[tid];
    // write sorted src (low 16b), two at a time
    u32* sb = (u32*)(sbuf + (size_t)b * BCAP);
    for (int i = tid; i * 2 < cnt; i += 256) {
        u32 lo = stage[i * 2] & 0xFFFFu;
        u32 hi = stage[i * 2 + 1] & 0xFFFFu;   // pad-safe: only read if 2i+1<2048
        sb[i] = lo | (hi << 16);
    }
}

// ---------------- fused conv (R8 structure, src-sorted edge lists) --------
// Block = bucket = M-tile (64 nodes). 8 waves. Gather: 16-lane group per node
// (4 nodes/wave, 2 q-iters), dwordx4 row reads, 4-deep register batches,
// float-bit unpack. GEMM: 8 waves as 2Mx4N; weights from global (L2-resident).
// k-map phi(g,i)=8g+i both operands; D: col=lane&15, row=(lane>>4)*4+reg.

template <bool F32OUT>
__global__ __launch_bounds__(512, 6) void conv_kernel(
    const u16* __restrict__ h, const u16* __restrict__ sbuf,
    const int* __restrict__ noff,
    const u16* __restrict__ WTa, const float* __restrict__ biasa,
    const u16* __restrict__ WTb, const float* __restrict__ biasb,
    void* __restrict__ outv)
{
    __shared__ u16 a_lds[64][136];   // 17.4 KB
    __shared__ u16 t_lds[64][136];   // 17.4 KB
    __shared__ u16 sorted[BCAP];     // 3 KB
    __shared__ int off[65];

    const int tid = threadIdx.x;
    const int lane = tid & 63;
    const int wv = tid >> 6;         // 0..7
    const int b = blockIdx.x;
    const int node0 = b * BNODES;
    const int nNodes = min(BNODES, NN - node0);
    const int g = lane >> 4;         // group 0..3
    const int l16 = lane & 15;

    // ---- phase 1: load sorted edge list + offsets ----
    if (tid < 65) off[tid] = noff[b * 65 + tid];
    __syncthreads();
    const int cnt = off[64];
    {
        const u32* sb = (const u32*)(sbuf + (size_t)b * BCAP);
        u32* so = (u32*)sorted;
        for (int i = tid; i * 2 < cnt; i += 512) so[i] = sb[i];
    }
    __syncthreads();

    // ---- phase 2: gather into a_lds (group g handles node q*4+g) ----
    const u16* hcol = h + l16 * 8;   // this lane's 8-feature slice

    for (int q = wv; q < 16; q += 8) {
        const int n = q * 4 + g;
        float4 acc0 = {0.f, 0.f, 0.f, 0.f};
        float4 acc1 = {0.f, 0.f, 0.f, 0.f};
        if (n < nNodes) {
            uint4 v = *reinterpret_cast<const uint4*>(hcol + (size_t)(node0 + n) * FD);
            ACCUM(v);   // self term
            const int end = off[n + 1];
            const int endm1 = end - 1;
            for (int e = off[n]; e < end; e += 4) {
                const int m = end - e;
                uint4 vv[4];
#pragma unroll
                for (int k = 0; k < 4; ++k) {
                    int ee = e + k; if (ee > endm1) ee = endm1;  // dup tail: L1-hit
                    vv[k] = *reinterpret_cast<const uint4*>(
                        hcol + (size_t)sorted[ee] * FD);
                }
                ACCUM(vv[0]);
                if (m > 1) ACCUM(vv[1]);
                if (m > 2) ACCUM(vv[2]);
                if (m > 3) ACCUM(vv[3]);
            }
        }
        uint4 o;
        o.x = (u32)f2b(acc0.x) | ((u32)f2b(acc0.y) << 16);
        o.y = (u32)f2b(acc0.z) | ((u32)f2b(acc0.w) << 16);
        o.z = (u32)f2b(acc1.x) | ((u32)f2b(acc1.y) << 16);
        o.w = (u32)f2b(acc1.z) | ((u32)f2b(acc1.w) << 16);
        *reinterpret_cast<uint4*>(&a_lds[n][l16 * 8]) = o;   // zeros for pad rows
    }
    __syncthreads();

    const int mbase = (wv >> 2) * 32;   // 0 or 32
    const int nbase = (wv & 3) * 32;    // 0,32,64,96

    // ---- phase 3: t = relu(a @ Wa + ba) ----
    f32x4 acc[2][2];
#pragma unroll
    for (int m = 0; m < 2; ++m)
#pragma unroll
        for (int nf = 0; nf < 2; ++nf) acc[m][nf] = (f32x4){0.f, 0.f, 0.f, 0.f};

#pragma unroll
    for (int k0 = 0; k0 < 4; ++k0) {
        const int kk = k0 * 32 + g * 8;
        bf16x8 a0 = *reinterpret_cast<const bf16x8*>(&a_lds[mbase + l16][kk]);
        bf16x8 a1 = *reinterpret_cast<const bf16x8*>(&a_lds[mbase + 16 + l16][kk]);
#pragma unroll
        for (int nf = 0; nf < 2; ++nf) {
            bf16x8 bb = *reinterpret_cast<const bf16x8*>(
                WTa + (size_t)(nbase + nf * 16 + l16) * FD + kk);
            acc[0][nf] = __builtin_amdgcn_mfma_f32_16x16x32_bf16(a0, bb, acc[0][nf], 0, 0, 0);
            acc[1][nf] = __builtin_amdgcn_mfma_f32_16x16x32_bf16(a1, bb, acc[1][nf], 0, 0, 0);
        }
    }

#pragma unroll
    for (int m = 0; m < 2; ++m) {
#pragma unroll
        for (int nf = 0; nf < 2; ++nf) {
            int col = nbase + nf * 16 + l16;
            float bc = biasa[col];
#pragma unroll
            for (int r = 0; r < 4; ++r) {
                int row = mbase + 16 * m + g * 4 + r;
                t_lds[row][col] = f2b(fmaxf(acc[m][nf][r] + bc, 0.f));
            }
        }
    }
    __syncthreads();

    // ---- phase 4: out = relu(t @ Wb + bb) ----
    f32x4 acc2[2][2];
#pragma unroll
    for (int m = 0; m < 2; ++m)
#pragma unroll
        for (int nf = 0; nf < 2; ++nf) acc2[m][nf] = (f32x4){0.f, 0.f, 0.f, 0.f};

#pragma unroll
    for (int k0 = 0; k0 < 4; ++k0) {
        const int kk = k0 * 32 + g * 8;
        bf16x8 a0 = *reinterpret_cast<const bf16x8*>(&t_lds[mbase + l16][kk]);
        bf16x8 a1 = *reinterpret_cast<const bf16x8*>(&t_lds[mbase + 16 + l16][kk]);
#pragma unroll
        for (int nf = 0; nf < 2; ++nf) {
            bf16x8 bb = *reinterpret_cast<const bf16x8*>(
                WTb + (size_t)(nbase + nf * 16 + l16) * FD + kk);
            acc2[0][nf] = __builtin_amdgcn_mfma_f32_16x16x32_bf16(a0, bb, acc2[0][nf], 0, 0, 0);
            acc2[1][nf] = __builtin_amdgcn_mfma_f32_16x16x32_bf16(a1, bb, acc2[1][nf], 0, 0, 0);
        }
    }

    if (F32OUT) {
        // f32 frag stores are already full-line (16 consecutive f32 = 64B)
#pragma unroll
        for (int m = 0; m < 2; ++m) {
#pragma unroll
            for (int nf = 0; nf < 2; ++nf) {
                int col = nbase + nf * 16 + l16;
                float bc = biasb[col];
#pragma unroll
                for (int r = 0; r < 4; ++r) {
                    int row = node0 + mbase + 16 * m + g * 4 + r;
                    if (row < NN) {
                        float v = fmaxf(acc2[m][nf][r] + bc, 0.f);
                        reinterpret_cast<float*>(outv)[(size_t)row * FD + col] = v;
                    }
                }
            }
        }
    } else {
        // stage bf16 result in t_lds (free after phase 4 reads), then
        // coalesced 16B/lane copy-out — avoids 2x partial-line writebacks.
        __syncthreads();
#pragma unroll
        for (int m = 0; m < 2; ++m) {
#pragma unroll
            for (int nf = 0; nf < 2; ++nf) {
                int col = nbase + nf * 16 + l16;
                float bc = biasb[col];
#pragma unroll
                for (int r = 0; r < 4; ++r) {
                    int row = mbase + 16 * m + g * 4 + r;
                    t_lds[row][col] = f2b(fmaxf(acc2[m][nf][r] + bc, 0.f));
                }
            }
        }
        __syncthreads();
        u16* outp = reinterpret_cast<u16*>(outv);
#pragma unroll
        for (int it = 0; it < 2; ++it) {
            int idx = tid + it * 512;
            int r = idx >> 4, c = (idx & 15) * 8;
            if (node0 + r < NN)
                *reinterpret_cast<uint4*>(outp + (size_t)(node0 + r) * FD + c) =
                    *reinterpret_cast<const uint4*>(&t_lds[r][c]);
        }
    }
}

extern "C" void kernel_launch(void* const* d_in, const int* in_sizes, int n_in,
                              void* d_out, int out_size, void* d_ws, size_t ws_size,
                              hipStream_t stream) {
    const float* x   = (const float*)d_in[0];
    const int*   ei  = (const int*)d_in[1];
    const float* W1a = (const float*)d_in[2];
    const float* b1a = (const float*)d_in[3];
    const float* W1b = (const float*)d_in[4];
    const float* b1b = (const float*)d_in[5];
    const float* W2a = (const float*)d_in[6];
    const float* b2a = (const float*)d_in[7];
    const float* W2b = (const float*)d_in[8];
    const float* b2b = (const float*)d_in[9];

    const size_t feat = (size_t)NN * FD;
    u16* xb = (u16*)d_ws;             // 12.8 MB (x bf16)
    u16* zb = xb + feat;              // 12.8 MB (h1 bf16)
    u16* wt = zb + feat;              // 128 KB
    int* gcnt = (int*)(wt + 4 * FD * FD);         // 1024 ints
    u32* ebuf = (u32*)(gcnt + 1024);              // NB*BCAP*4 = 4.80 MB
    u16* sbuf = (u16*)(ebuf + (size_t)NB * BCAP); // NB*BCAP*2 = 2.40 MB
    int* noff = (int*)(sbuf + (size_t)NB * BCAP); // NB*65*4 = 204 KB

    const int cBlocks = (int)(feat / (256 * 8));  // 3125

    convert_x_kernel<<<cBlocks, 256, 0, stream>>>(x, xb);
    convert_w_kernel<<<5, 256, 0, stream>>>(W1a, W1b, W2a, W2b, wt, gcnt);

    bin_kernel<<<NWG_BIN, 256, 0, stream>>>(ei, ebuf, gcnt);
    sort_kernel<<<NB, 256, 0, stream>>>(ebuf, gcnt, sbuf, noff);

    // conv1: xb -> zb (bf16)
    conv_kernel<false><<<NB, 512, 0, stream>>>(
        xb, sbuf, noff, wt, b1a, wt + 1 * FD * FD, b1b, zb);
    // conv2: zb -> d_out (fp32)
    conv_kernel<true><<<NB, 512, 0, stream>>>(
        zb, sbuf, noff, wt + 2 * FD * FD, b2a, wt + 3 * FD * FD, b2b, (float*)d_out);
}

// Round 15
// 125.065 us; speedup vs baseline: 1.3247x; 1.2683x over previous
//
#include <hip/hip_runtime.h>

// GIN: 2x GINConv(eps=0), N=50000, E=800000, d=128. bf16 + MFMA.
// R15: R8 conv (best ladder point, 132.8us) with the preprocessing collapsed:
// (1) sort_kernel deleted -- counting sort moved into conv phase 0, staging
// the packed edges in LDS aliased over t_lds (unused until GEMM1 output);
// (2) convert_x + convert_w + gcnt-zero fused into one prep_kernel.
// Pipeline: prep -> bin -> conv1 -> conv2 (4 dispatches, was 6+memset).
// Gather itself untouched: 5 structural levers (TLP/ILP/requests/balance/
// src-order) all nulled; it is L2-miss-service bound (~34us of 76MB @2.3TB/s).
// ws: [ xb 12.8M | zb 12.8M | wt 128K | gcnt 4K | ebuf 4.8M ]

#define NN 50000
#define NE 800000
#define FD 128
#define BNODES 64
#define NB 782           // ceil(NN/64); bucket 781 has 16 nodes
#define BCAP 1536        // max edges/bucket: mean 1024, sigma 32 -> +16 sigma
#define EPW 4096
#define NWG_BIN 196      // ceil(NE/EPW)
#define XBLK 3125        // convert-x blocks in prep

typedef unsigned short u16;
typedef unsigned int u32;
typedef __attribute__((ext_vector_type(8))) short bf16x8;
typedef __attribute__((ext_vector_type(4))) float f32x4;

static __device__ __forceinline__ u16 f2b(float f) {
    u32 x = __float_as_uint(f);
    u32 r = x + 0x7FFFu + ((x >> 16) & 1u);   // RNE
    return (u16)(r >> 16);
}

// unpack-accumulate a uint4 (8 bf16) into acc0/acc1 via exact float-bit tricks
#define ACCUM(v) do { \
    acc0.x += __uint_as_float((v).x << 16); \
    acc0.y += __uint_as_float((v).x & 0xFFFF0000u); \
    acc0.z += __uint_as_float((v).y << 16); \
    acc0.w += __uint_as_float((v).y & 0xFFFF0000u); \
    acc1.x += __uint_as_float((v).z << 16); \
    acc1.y += __uint_as_float((v).z & 0xFFFF0000u); \
    acc1.z += __uint_as_float((v).w << 16); \
    acc1.w += __uint_as_float((v).w & 0xFFFF0000u); } while (0)

// ---------------- prep: x->bf16, W->WT bf16, gcnt=0 (one kernel) ----------

__global__ __launch_bounds__(256) void prep_kernel(
    const float* __restrict__ x, u16* __restrict__ xb,
    const float* __restrict__ w0, const float* __restrict__ w1,
    const float* __restrict__ w2, const float* __restrict__ w3,
    u16* __restrict__ wt, int* __restrict__ gcnt)
{
    const int b = blockIdx.x;
    if (b < XBLK) {
        int gid = b * 256 + threadIdx.x;
        size_t base = (size_t)gid * 8;
        float4 a = *reinterpret_cast<const float4*>(x + base);
        float4 c = *reinterpret_cast<const float4*>(x + base + 4);
        u32 q0 = (u32)f2b(a.x) | ((u32)f2b(a.y) << 16);
        u32 q1 = (u32)f2b(a.z) | ((u32)f2b(a.w) << 16);
        u32 q2 = (u32)f2b(c.x) | ((u32)f2b(c.y) << 16);
        u32 q3 = (u32)f2b(c.z) | ((u32)f2b(c.w) << 16);
        uint4 o = {q0, q1, q2, q3};
        *reinterpret_cast<uint4*>(xb + base) = o;
    } else if (b < XBLK + 4) {
        int w = b - XBLK;
        const float* W = (w == 0) ? w0 : (w == 1) ? w1 : (w == 2) ? w2 : w3;
        u16* out = wt + (size_t)w * FD * FD;
        for (int idx = threadIdx.x; idx < FD * FD; idx += 256) {
            int n = idx >> 7, k = idx & 127;
            out[idx] = f2b(W[k * FD + n]);   // WT[n][k] = W[k][n]
        }
    } else {
        for (int i = threadIdx.x; i < NB; i += 256) gcnt[i] = 0;
    }
}

// ---------------- bucket binning (64-node buckets) ----------------
// Edges grouped by bucket b = dst>>6 into ebuf[b*BCAP ...], packed
// u32 = src | (dst_local << 16). LDS-staged, contiguous flush.

__global__ __launch_bounds__(256) void bin_kernel(
    const int* __restrict__ ei, u32* __restrict__ ebuf, int* __restrict__ gcnt)
{
    __shared__ int cnt[1024];
    __shared__ int lofs[1024];
    __shared__ int cur[1024];
    __shared__ int gb[1024];
    __shared__ int csum[16];
    __shared__ int cofs[16];
    __shared__ u32 vals[EPW];
    __shared__ u16 bkt[EPW];

    const int tid = threadIdx.x, lane = tid & 63, wv = tid >> 6;
    const int e0 = blockIdx.x * EPW;
    const int nE = min(EPW, NE - e0);
    const int* dstp = ei + NE;

    for (int i = tid; i < 1024; i += 256) { cnt[i] = 0; cur[i] = 0; }
    __syncthreads();

    for (int k = 0; k < EPW / 256; ++k) {
        int e = e0 + k * 256 + tid;
        if (e < NE) atomicAdd(&cnt[(u32)dstp[e] >> 6], 1);
    }
    __syncthreads();

    // exclusive scan over 1024 slots (16 chunks of 64)
    for (int cc = 0; cc < 4; ++cc) {
        int c = wv + cc * 4;
        int i = c * 64 + lane;
        int v = cnt[i];
        int sc = v;
#pragma unroll
        for (int s = 1; s < 64; s <<= 1) {
            int t = __shfl_up(sc, s);
            if (lane >= s) sc += t;
        }
        lofs[i] = sc - v;
        if (lane == 63) csum[c] = sc;
    }
    __syncthreads();
    if (wv == 0) {
        int s = (lane < 16) ? csum[lane] : 0;
        int sc = s;
#pragma unroll
        for (int st = 1; st < 16; st <<= 1) {
            int u = __shfl_up(sc, st);
            if (lane >= st) sc += u;
        }
        if (lane < 16) cofs[lane] = sc - s;
    }
    __syncthreads();
    for (int cc = 0; cc < 4; ++cc) {
        int c = wv + cc * 4;
        lofs[c * 64 + lane] += cofs[c];
    }
    __syncthreads();

    // place (bucket-grouped in LDS)
    for (int k = 0; k < EPW / 256; ++k) {
        int e = e0 + k * 256 + tid;
        if (e < NE) {
            int s = ei[e];
            u32 d = (u32)dstp[e];
            int b = d >> 6;
            int p = lofs[b] + atomicAdd(&cur[b], 1);
            vals[p] = (u32)s | ((d & 63u) << 16);
            bkt[p] = (u16)b;
        }
    }
    __syncthreads();

    // claim global chunks
    for (int b = tid; b < NB; b += 256) {
        int c = cur[b];
        gb[b] = c ? atomicAdd(&gcnt[b], c) : 0;
    }
    __syncthreads();

    // flush bucket-grouped -> contiguous runs
    for (int idx = tid; idx < nE; idx += 256) {
        int b = bkt[idx];
        ebuf[(size_t)b * BCAP + gb[b] + (idx - lofs[b])] = vals[idx];
    }
}

// ---------------- fused conv: in-LDS counting sort + gather + MLP ----------
// Block = bucket = M-tile (64 nodes). 8 waves.
// Phase 0: load packed edges (stage aliases t_lds), counting-sort to u16 src
//          lists grouped by dst_local.
// Phase 2: gather — 16-lane group per node (4/wave, 2 q-iters), dwordx4 row
//          reads, 4-deep register batches, float-bit unpack.
// Phase 3/4: two MFMA GEMMs; weights read as B-frags from global (L2-hot).
// k-map phi(g,i)=8g+i both operands; D: col=lane&15, row=(lane>>4)*4+reg.

template <bool F32OUT>
__global__ __launch_bounds__(512, 6) void conv_kernel(
    const u16* __restrict__ h, const u32* __restrict__ ebuf,
    const int* __restrict__ gcnt,
    const u16* __restrict__ WTa, const float* __restrict__ biasa,
    const u16* __restrict__ WTb, const float* __restrict__ biasb,
    void* __restrict__ outv)
{
    __shared__ u16 a_lds[64][136];   // 17.4 KB
    __shared__ u16 t_lds[64][136];   // 17.4 KB (phase 0: aliased as stage[])
    __shared__ u16 sorted[BCAP];     // 3 KB
    __shared__ int off[65];
    __shared__ int cnt64[64];
    __shared__ int cur64[64];

    const int tid = threadIdx.x;
    const int lane = tid & 63;
    const int wv = tid >> 6;         // 0..7
    const int b = blockIdx.x;
    const int node0 = b * BNODES;
    const int nNodes = min(BNODES, NN - node0);
    const int g = lane >> 4;         // group 0..3
    const int l16 = lane & 15;

    u32* stage = reinterpret_cast<u32*>(&t_lds[0][0]);   // 1536*4B <= 17.4KB

    // ---- phase 0: load packed edges + counting sort by dst_local ----
    const int cnt = gcnt[b];
    if (tid < 64) cnt64[tid] = 0;
    __syncthreads();
    {
        const u32* eb = ebuf + (size_t)b * BCAP;
        for (int e = tid; e < cnt; e += 512) {
            u32 v = eb[e];
            stage[e] = v;
            atomicAdd(&cnt64[v >> 16], 1);
        }
    }
    __syncthreads();
    if (wv == 0) {
        int v = cnt64[lane];
        int sc = v;
#pragma unroll
        for (int s = 1; s < 64; s <<= 1) {
            int t = __shfl_up(sc, s);
            if (lane >= s) sc += t;
        }
        off[lane + 1] = sc;
        cur64[lane] = sc - v;
        if (lane == 0) off[0] = 0;
    }
    __syncthreads();
    for (int e = tid; e < cnt; e += 512) {
        u32 v = stage[e];
        int pos = atomicAdd(&cur64[v >> 16], 1);
        sorted[pos] = (u16)(v & 0xFFFFu);   // src < 50000 fits u16
    }
    __syncthreads();

    // ---- phase 2: gather into a_lds (group g handles node q*4+g) ----
    const u16* hcol = h + l16 * 8;   // this lane's 8-feature slice

    for (int q = wv; q < 16; q += 8) {
        const int n = q * 4 + g;
        float4 acc0 = {0.f, 0.f, 0.f, 0.f};
        float4 acc1 = {0.f, 0.f, 0.f, 0.f};
        if (n < nNodes) {
            uint4 v = *reinterpret_cast<const uint4*>(hcol + (size_t)(node0 + n) * FD);
            ACCUM(v);   // self term
            const int end = off[n + 1];
            const int endm1 = end - 1;
            for (int e = off[n]; e < end; e += 4) {
                const int m = end - e;
                uint4 vv[4];
#pragma unroll
                for (int k = 0; k < 4; ++k) {
                    int ee = e + k; if (ee > endm1) ee = endm1;  // dup tail: L1-hit
                    vv[k] = *reinterpret_cast<const uint4*>(
                        hcol + (size_t)sorted[ee] * FD);
                }
                ACCUM(vv[0]);
                if (m > 1) ACCUM(vv[1]);
                if (m > 2) ACCUM(vv[2]);
                if (m > 3) ACCUM(vv[3]);
            }
        }
        uint4 o;
        o.x = (u32)f2b(acc0.x) | ((u32)f2b(acc0.y) << 16);
        o.y = (u32)f2b(acc0.z) | ((u32)f2b(acc0.w) << 16);
        o.z = (u32)f2b(acc1.x) | ((u32)f2b(acc1.y) << 16);
        o.w = (u32)f2b(acc1.z) | ((u32)f2b(acc1.w) << 16);
        *reinterpret_cast<uint4*>(&a_lds[n][l16 * 8]) = o;   // zeros for pad rows
    }
    __syncthreads();   // stage (t_lds) fully consumed beyond this point

    const int mbase = (wv >> 2) * 32;   // 0 or 32
    const int nbase = (wv & 3) * 32;    // 0,32,64,96

    // ---- phase 3: t = relu(a @ Wa + ba) ----
    f32x4 acc[2][2];
#pragma unroll
    for (int m = 0; m < 2; ++m)
#pragma unroll
        for (int nf = 0; nf < 2; ++nf) acc[m][nf] = (f32x4){0.f, 0.f, 0.f, 0.f};

#pragma unroll
    for (int k0 = 0; k0 < 4; ++k0) {
        const int kk = k0 * 32 + g * 8;
        bf16x8 a0 = *reinterpret_cast<const bf16x8*>(&a_lds[mbase + l16][kk]);
        bf16x8 a1 = *reinterpret_cast<const bf16x8*>(&a_lds[mbase + 16 + l16][kk]);
#pragma unroll
        for (int nf = 0; nf < 2; ++nf) {
            bf16x8 bb = *reinterpret_cast<const bf16x8*>(
                WTa + (size_t)(nbase + nf * 16 + l16) * FD + kk);
            acc[0][nf] = __builtin_amdgcn_mfma_f32_16x16x32_bf16(a0, bb, acc[0][nf], 0, 0, 0);
            acc[1][nf] = __builtin_amdgcn_mfma_f32_16x16x32_bf16(a1, bb, acc[1][nf], 0, 0, 0);
        }
    }

#pragma unroll
    for (int m = 0; m < 2; ++m) {
#pragma unroll
        for (int nf = 0; nf < 2; ++nf) {
            int col = nbase + nf * 16 + l16;
            float bc = biasa[col];
#pragma unroll
            for (int r = 0; r < 4; ++r) {
                int row = mbase + 16 * m + g * 4 + r;
                t_lds[row][col] = f2b(fmaxf(acc[m][nf][r] + bc, 0.f));
            }
        }
    }
    __syncthreads();

    // ---- phase 4: out = relu(t @ Wb + bb) ----
    f32x4 acc2[2][2];
#pragma unroll
    for (int m = 0; m < 2; ++m)
#pragma unroll
        for (int nf = 0; nf < 2; ++nf) acc2[m][nf] = (f32x4){0.f, 0.f, 0.f, 0.f};

#pragma unroll
    for (int k0 = 0; k0 < 4; ++k0) {
        const int kk = k0 * 32 + g * 8;
        bf16x8 a0 = *reinterpret_cast<const bf16x8*>(&t_lds[mbase + l16][kk]);
        bf16x8 a1 = *reinterpret_cast<const bf16x8*>(&t_lds[mbase + 16 + l16][kk]);
#pragma unroll
        for (int nf = 0; nf < 2; ++nf) {
            bf16x8 bb = *reinterpret_cast<const bf16x8*>(
                WTb + (size_t)(nbase + nf * 16 + l16) * FD + kk);
            acc2[0][nf] = __builtin_amdgcn_mfma_f32_16x16x32_bf16(a0, bb, acc2[0][nf], 0, 0, 0);
            acc2[1][nf] = __builtin_amdgcn_mfma_f32_16x16x32_bf16(a1, bb, acc2[1][nf], 0, 0, 0);
        }
    }

    if (F32OUT) {
        // f32 frag stores are already full-line (16 consecutive f32 = 64B)
#pragma unroll
        for (int m = 0; m < 2; ++m) {
#pragma unroll
            for (int nf = 0; nf < 2; ++nf) {
                int col = nbase + nf * 16 + l16;
                float bc = biasb[col];
#pragma unroll
                for (int r = 0; r < 4; ++r) {
                    int row = node0 + mbase + 16 * m + g * 4 + r;
                    if (row < NN) {
                        float v = fmaxf(acc2[m][nf][r] + bc, 0.f);
                        reinterpret_cast<float*>(outv)[(size_t)row * FD + col] = v;
                    }
                }
            }
        }
    } else {
        // stage bf16 result in a_lds (consumed), coalesced 16B/lane copy-out
        __syncthreads();
#pragma unroll
        for (int m = 0; m < 2; ++m) {
#pragma unroll
            for (int nf = 0; nf < 2; ++nf) {
                int col = nbase + nf * 16 + l16;
                float bc = biasb[col];
#pragma unroll
                for (int r = 0; r < 4; ++r) {
                    int row = mbase + 16 * m + g * 4 + r;
                    a_lds[row][col] = f2b(fmaxf(acc2[m][nf][r] + bc, 0.f));
                }
            }
        }
        __syncthreads();
        u16* outp = reinterpret_cast<u16*>(outv);
#pragma unroll
        for (int it = 0; it < 2; ++it) {
            int idx = tid + it * 512;
            int r = idx >> 4, c = (idx & 15) * 8;
            if (node0 + r < NN)
                *reinterpret_cast<uint4*>(outp + (size_t)(node0 + r) * FD + c) =
                    *reinterpret_cast<const uint4*>(&a_lds[r][c]);
        }
    }
}

extern "C" void kernel_launch(void* const* d_in, const int* in_sizes, int n_in,
                              void* d_out, int out_size, void* d_ws, size_t ws_size,
                              hipStream_t stream) {
    const float* x   = (const float*)d_in[0];
    const int*   ei  = (const int*)d_in[1];
    const float* W1a = (const float*)d_in[2];
    const float* b1a = (const float*)d_in[3];
    const float* W1b = (const float*)d_in[4];
    const float* b1b = (const float*)d_in[5];
    const float* W2a = (const float*)d_in[6];
    const float* b2a = (const float*)d_in[7];
    const float* W2b = (const float*)d_in[8];
    const float* b2b = (const float*)d_in[9];

    const size_t feat = (size_t)NN * FD;
    u16* xb = (u16*)d_ws;             // 12.8 MB (x bf16)
    u16* zb = xb + feat;              // 12.8 MB (h1 bf16)
    u16* wt = zb + feat;              // 128 KB
    int* gcnt = (int*)(wt + 4 * FD * FD);         // 1024 ints
    u32* ebuf = (u32*)(gcnt + 1024);              // NB*BCAP*4 = 4.80 MB

    // 1) x->bf16, W->WT bf16, gcnt=0
    prep_kernel<<<XBLK + 5, 256, 0, stream>>>(x, xb, W1a, W1b, W2a, W2b, wt, gcnt);
    // 2) bin edges into 64-node buckets (packed src|dst_local)
    bin_kernel<<<NWG_BIN, 256, 0, stream>>>(ei, ebuf, gcnt);
    // 3) conv1: xb -> zb (bf16)
    conv_kernel<false><<<NB, 512, 0, stream>>>(
        xb, ebuf, gcnt, wt, b1a, wt + 1 * FD * FD, b1b, zb);
    // 4) conv2: zb -> d_out (fp32)
    conv_kernel<true><<<NB, 512, 0, stream>>>(
        zb, ebuf, gcnt, wt + 2 * FD * FD, b2a, wt + 3 * FD * FD, b2b, (float*)d_out);
}